// Round 1
// baseline (605.363 us; speedup 1.0000x reference)
//
#include <hip/hip_runtime.h>
#include <hip/hip_bf16.h>

typedef float f32x4 __attribute__((ext_vector_type(4)));
typedef short s16x8 __attribute__((ext_vector_type(8)));

#define MFMA_BF16(a, b, c) __builtin_amdgcn_mfma_f32_16x16x32_bf16((a), (b), (c), 0, 0, 0)

// ---------- helpers ----------
__device__ __forceinline__ ushort f2bf(float f) {
  uint u = __builtin_bit_cast(uint, f);
  u += 0x7FFFu + ((u >> 16) & 1u);
  return (ushort)(u >> 16);
}
__device__ __forceinline__ uint pack2bf(float a, float b) {
  return (uint)f2bf(a) | ((uint)f2bf(b) << 16);
}
// exp(s - 30) written identically in stats and attn kernels
__device__ __forceinline__ float pexp(float s) {
  return exp2f(fmaf(s, 1.4426950408889634f, -43.2808512266689f));
}

// ---------- ws layout (bytes) ----------
#define WS_XT    0UL
#define WS_D     16777216UL
#define WS_BT    33554432UL
#define WS_CT    35651584UL
#define WS_WCAT  37748736UL
#define WS_BCAT  38404096UL
#define WS_LINV  38406656UL

// ---------- kernel 1: pack weights to bf16 [640][512] + bias concat ----------
__global__ void k_prep_w(const float* __restrict__ Wb, const float* __restrict__ bb,
                         const float* __restrict__ Wc, const float* __restrict__ bc,
                         const float* __restrict__ Wd, const float* __restrict__ bd,
                         ushort* __restrict__ Wcat, float* __restrict__ bcat) {
  int idx = blockIdx.x * 256 + threadIdx.x;
  if (idx < 640 * 512) {
    int m = idx >> 9, k = idx & 511;
    float v = (m < 64) ? Wb[m * 512 + k] : (m < 128) ? Wc[(m - 64) * 512 + k] : Wd[(m - 128) * 512 + k];
    Wcat[idx] = f2bf(v);
  }
  if (idx < 640) {
    bcat[idx] = (idx < 64) ? bb[idx] : (idx < 128) ? bc[idx - 64] : bd[idx - 128];
  }
}

// ---------- kernel 2: transpose x [B][512][4096] f32 -> xT [B][4096][512] bf16 ----------
__global__ __launch_bounds__(256) void k_prep_xt(const float* __restrict__ x, ushort* __restrict__ xT) {
  __shared__ float tile[64][65];
  int bx = blockIdx.x;
  int b = bx >> 9;                  // 8*64 = 512 tiles per batch
  int c0 = ((bx >> 6) & 7) * 64;
  int n0 = (bx & 63) * 64;
  int t = threadIdx.x;
  const float* xb = x + (size_t)b * 512 * 4096;
#pragma unroll
  for (int p = 0; p < 4; ++p) {
    int cl = (t >> 4) + 16 * p;
    int nf = (t & 15) * 4;
    float4 v = *reinterpret_cast<const float4*>(xb + (size_t)(c0 + cl) * 4096 + n0 + nf);
    tile[cl][nf + 0] = v.x; tile[cl][nf + 1] = v.y; tile[cl][nf + 2] = v.z; tile[cl][nf + 3] = v.w;
  }
  __syncthreads();
  ushort* dst = xT + (size_t)b * 4096 * 512;
#pragma unroll
  for (int q = 0; q < 2; ++q) {
    int ch = t + 256 * q;
    int nl = ch >> 3;
    int cf = (ch & 7) * 8;
    uint4 o;
    o.x = pack2bf(tile[cf + 0][nl], tile[cf + 1][nl]);
    o.y = pack2bf(tile[cf + 2][nl], tile[cf + 3][nl]);
    o.z = pack2bf(tile[cf + 4][nl], tile[cf + 5][nl]);
    o.w = pack2bf(tile[cf + 6][nl], tile[cf + 7][nl]);
    *reinterpret_cast<uint4*>(dst + (size_t)(n0 + nl) * 512 + c0 + cf) = o;
  }
}

// ---------- kernel 3: projection GEMM [640 x 4096, K=512] per batch ----------
// rows 0-63 -> bT[n][k] (transposed), 64-127 -> cT[n][k], 128-639 -> d[c][n]
__global__ __launch_bounds__(256) void k_proj(const ushort* __restrict__ Wcat, const float* __restrict__ bcat,
                                              const ushort* __restrict__ xT, ushort* __restrict__ bT,
                                              ushort* __restrict__ cT, ushort* __restrict__ dmat) {
  int bx = blockIdx.x;
  int b = bx / 160;
  int r = bx % 160;
  int m0 = (r >> 5) * 128;    // 5 m-tiles
  int n0 = (r & 31) * 128;    // 32 n-tiles
  int t = threadIdx.x, l = t & 63, w = t >> 6;
  int wm = w >> 1, wn = w & 1, g = l >> 4, l15 = l & 15;
  const ushort* xb = xT + (size_t)b * 4096 * 512;
  f32x4 acc[4][4] = {};
  for (int k0 = 0; k0 < 512; k0 += 32) {
    s16x8 a[4], bf[4];
#pragma unroll
    for (int mt = 0; mt < 4; ++mt)
      a[mt] = *reinterpret_cast<const s16x8*>(Wcat + (size_t)(m0 + 64 * wm + 16 * mt + l15) * 512 + k0 + 8 * g);
#pragma unroll
    for (int nt = 0; nt < 4; ++nt)
      bf[nt] = *reinterpret_cast<const s16x8*>(xb + (size_t)(n0 + 64 * wn + 16 * nt + l15) * 512 + k0 + 8 * g);
#pragma unroll
    for (int mt = 0; mt < 4; ++mt)
#pragma unroll
      for (int nt = 0; nt < 4; ++nt)
        acc[mt][nt] = MFMA_BF16(a[mt], bf[nt], acc[mt][nt]);
  }
#pragma unroll
  for (int mt = 0; mt < 4; ++mt) {
    int mbase = m0 + 64 * wm + 16 * mt + 4 * g;
#pragma unroll
    for (int nt = 0; nt < 4; ++nt) {
      int n = n0 + 64 * wn + 16 * nt + l15;
      float v0 = acc[mt][nt][0] + bcat[mbase + 0];
      float v1 = acc[mt][nt][1] + bcat[mbase + 1];
      float v2 = acc[mt][nt][2] + bcat[mbase + 2];
      float v3 = acc[mt][nt][3] + bcat[mbase + 3];
      if (mbase < 64) {
        uint2 u; u.x = pack2bf(v0, v1); u.y = pack2bf(v2, v3);
        *reinterpret_cast<uint2*>(bT + ((size_t)b * 4096 + n) * 64 + mbase) = u;
      } else if (mbase < 128) {
        uint2 u; u.x = pack2bf(v0, v1); u.y = pack2bf(v2, v3);
        *reinterpret_cast<uint2*>(cT + ((size_t)b * 4096 + n) * 64 + (mbase - 64)) = u;
      } else {
        size_t base = ((size_t)b * 512 + (mbase - 128)) * 4096 + n;
        dmat[base + 0 * 4096] = f2bf(v0);
        dmat[base + 1 * 4096] = f2bf(v1);
        dmat[base + 2 * 4096] = f2bf(v2);
        dmat[base + 3 * 4096] = f2bf(v3);
      }
    }
  }
}

// ---------- kernel 4: row-sum stats  linv[b][i] = 1 / sum_j exp(s_ij - 30) ----------
__global__ __launch_bounds__(512) void k_stats(const ushort* __restrict__ bT, const ushort* __restrict__ cT,
                                               float* __restrict__ linv) {
  __shared__ float lsum[64];
  int bx = blockIdx.x;
  int b = bx >> 6;
  int i0 = (bx & 63) * 64;
  int t = threadIdx.x, l = t & 63, w = t >> 6;
  int wm = w >> 1, wn = w & 1, g = l >> 4, l15 = l & 15;
  if (t < 64) lsum[t] = 0.f;
  __syncthreads();
  const ushort* bTb = bT + (size_t)b * 4096 * 64;
  const ushort* cTb = cT + (size_t)b * 4096 * 64;
  const ushort* ar = bTb + (size_t)(i0 + 16 * wm + l15) * 64 + 8 * g;
  s16x8 a0 = *reinterpret_cast<const s16x8*>(ar);
  s16x8 a1 = *reinterpret_cast<const s16x8*>(ar + 32);
  float lacc[4] = {0.f, 0.f, 0.f, 0.f};
  for (int it = 0; it < 32; ++it) {
    int jb = 64 * wn + 128 * it;
#pragma unroll
    for (int nt = 0; nt < 4; ++nt) {
      const ushort* cr = cTb + (size_t)(jb + 16 * nt + l15) * 64 + 8 * g;
      s16x8 b0 = *reinterpret_cast<const s16x8*>(cr);
      s16x8 b1 = *reinterpret_cast<const s16x8*>(cr + 32);
      f32x4 s = {0.f, 0.f, 0.f, 0.f};
      s = MFMA_BF16(a0, b0, s);
      s = MFMA_BF16(a1, b1, s);
#pragma unroll
      for (int rr = 0; rr < 4; ++rr) lacc[rr] += pexp(s[rr]);
    }
  }
#pragma unroll
  for (int off = 1; off < 16; off <<= 1)
#pragma unroll
    for (int rr = 0; rr < 4; ++rr) lacc[rr] += __shfl_xor(lacc[rr], off);
  if (l15 == 0) {
#pragma unroll
    for (int rr = 0; rr < 4; ++rr) atomicAdd(&lsum[16 * wm + 4 * g + rr], lacc[rr]);
  }
  __syncthreads();
  if (t < 64) linv[(size_t)b * 4096 + i0 + t] = 1.0f / fmaxf(lsum[t], 1e-30f);
}

// ---------- kernel 5: fused  Y = d . softmaxP(bT,cT) ; out = x + Y ----------
// block tile: 128 c-rows x 128 j-cols, K-loop over i in steps of 64. 8 waves (4x2).
__global__ __launch_bounds__(512) void k_attn(const ushort* __restrict__ bT, const ushort* __restrict__ cT,
                                              const ushort* __restrict__ dmat, const float* __restrict__ linv,
                                              const float* __restrict__ x, float* __restrict__ out) {
  // padded rows: 136 B stride (34 dwords -> conflict-free b128 reads)
  __shared__ char lds_raw[128 * 136 * 2];
  char* cT_lds = lds_raw;               // [128 j][64 k bf16], stride 136B
  char* PT     = lds_raw + 128 * 136;   // [128 j][64 i bf16], stride 136B
  int bx = blockIdx.x;
  int b = bx >> 7;                      // 4*32 = 128 blocks per batch
  int m0 = ((bx >> 5) & 3) * 128;
  int n0 = (bx & 31) * 128;
  int t = threadIdx.x, l = t & 63, w = t >> 6;
  int wm = w >> 1, wn = w & 1, g = l >> 4, l15 = l & 15;
  const ushort* bTb = bT + (size_t)b * 4096 * 64;
  const ushort* cTb = cT + (size_t)b * 4096 * 64;
  const ushort* db  = dmat + (size_t)b * 512 * 4096;
  const float*  lvb = linv + (size_t)b * 4096;

  // stage cT block-tile [128][64] into padded LDS
#pragma unroll
  for (int q = 0; q < 2; ++q) {
    int id = t + 512 * q;
    int row = id >> 3, kc = id & 7;
    s16x8 v = *reinterpret_cast<const s16x8*>(cTb + (size_t)(n0 + row) * 64 + kc * 8);
    *reinterpret_cast<s16x8*>(cT_lds + row * 136 + kc * 16) = v;
  }
  __syncthreads();

  f32x4 yacc[2][4] = {};
  for (int i0 = 0; i0 < 4096; i0 += 64) {
    // ---- scores: S[64 i x 128 j]; wave (wm,wn) does i rows [16wm,+16), j cols [64wn,+64)
    const ushort* ar = bTb + (size_t)(i0 + 16 * wm + l15) * 64 + 8 * g;
    s16x8 a0 = *reinterpret_cast<const s16x8*>(ar);
    s16x8 a1 = *reinterpret_cast<const s16x8*>(ar + 32);
    float4 lv = *reinterpret_cast<const float4*>(lvb + i0 + 16 * wm + 4 * g);
#pragma unroll
    for (int nt = 0; nt < 4; ++nt) {
      int jr = 64 * wn + 16 * nt + l15;
      s16x8 b0 = *reinterpret_cast<const s16x8*>(cT_lds + jr * 136 + 16 * g);
      s16x8 b1 = *reinterpret_cast<const s16x8*>(cT_lds + jr * 136 + 64 + 16 * g);
      f32x4 s = {0.f, 0.f, 0.f, 0.f};
      s = MFMA_BF16(a0, b0, s);
      s = MFMA_BF16(a1, b1, s);
      float p0 = pexp(s[0]) * lv.x;
      float p1 = pexp(s[1]) * lv.y;
      float p2 = pexp(s[2]) * lv.z;
      float p3 = pexp(s[3]) * lv.w;
      uint2 u; u.x = pack2bf(p0, p1); u.y = pack2bf(p2, p3);
      *reinterpret_cast<uint2*>(PT + jr * 136 + (16 * wm + 4 * g) * 2) = u;
    }
    __syncthreads();
    // ---- PV: Y[128 c x 128 j] += d[:, i0..i0+64] * P ; wave does rows [32wm,+32), cols [64wn,+64)
#pragma unroll
    for (int ks = 0; ks < 2; ++ks) {
      s16x8 av0 = *reinterpret_cast<const s16x8*>(db + (size_t)(m0 + 32 * wm + l15) * 4096 + i0 + 32 * ks + 8 * g);
      s16x8 av1 = *reinterpret_cast<const s16x8*>(db + (size_t)(m0 + 32 * wm + 16 + l15) * 4096 + i0 + 32 * ks + 8 * g);
#pragma unroll
      for (int nt = 0; nt < 4; ++nt) {
        int jr = 64 * wn + 16 * nt + l15;
        s16x8 bv = *reinterpret_cast<const s16x8*>(PT + jr * 136 + 64 * ks + 16 * g);
        yacc[0][nt] = MFMA_BF16(av0, bv, yacc[0][nt]);
        yacc[1][nt] = MFMA_BF16(av1, bv, yacc[1][nt]);
      }
    }
    __syncthreads();
  }
  // ---- epilogue: out = x + Y
#pragma unroll
  for (int mt = 0; mt < 2; ++mt) {
    int cbase = m0 + 32 * wm + 16 * mt + 4 * g;
#pragma unroll
    for (int nt = 0; nt < 4; ++nt) {
      int n = n0 + 64 * wn + 16 * nt + l15;
#pragma unroll
      for (int rr = 0; rr < 4; ++rr) {
        size_t idx = ((size_t)b * 512 + cbase + rr) * 4096 + n;
        out[idx] = x[idx] + yacc[mt][nt][rr];
      }
    }
  }
}

extern "C" void kernel_launch(void* const* d_in, const int* in_sizes, int n_in,
                              void* d_out, int out_size, void* d_ws, size_t ws_size,
                              hipStream_t stream) {
  const float* x  = (const float*)d_in[0];
  const float* Wb = (const float*)d_in[1];
  const float* bb = (const float*)d_in[2];
  const float* Wc = (const float*)d_in[3];
  const float* bc = (const float*)d_in[4];
  const float* Wd = (const float*)d_in[5];
  const float* bd = (const float*)d_in[6];
  char* ws = (char*)d_ws;
  ushort* xT   = (ushort*)(ws + WS_XT);
  ushort* dmat = (ushort*)(ws + WS_D);
  ushort* bT   = (ushort*)(ws + WS_BT);
  ushort* cT   = (ushort*)(ws + WS_CT);
  ushort* Wcat = (ushort*)(ws + WS_WCAT);
  float*  bcat = (float*)(ws + WS_BCAT);
  float*  linv = (float*)(ws + WS_LINV);
  float*  out  = (float*)d_out;

  k_prep_w<<<1280, 256, 0, stream>>>(Wb, bb, Wc, bc, Wd, bd, Wcat, bcat);
  k_prep_xt<<<2048, 256, 0, stream>>>(x, xT);
  k_proj<<<640, 256, 0, stream>>>(Wcat, bcat, xT, bT, cT, dmat);
  k_stats<<<256, 512, 0, stream>>>(bT, cT, linv);
  k_attn<<<512, 512, 0, stream>>>(bT, cT, dmat, linv, x, out);
}

// Round 2
// 588.784 us; speedup vs baseline: 1.0282x; 1.0282x over previous
//
#include <hip/hip_runtime.h>
#include <hip/hip_bf16.h>

typedef float f32x4 __attribute__((ext_vector_type(4)));
typedef short s16x8 __attribute__((ext_vector_type(8)));

#define MFMA_BF16(a, b, c) __builtin_amdgcn_mfma_f32_16x16x32_bf16((a), (b), (c), 0, 0, 0)

// ---------- helpers ----------
__device__ __forceinline__ ushort f2bf(float f) {
  uint u = __builtin_bit_cast(uint, f);
  u += 0x7FFFu + ((u >> 16) & 1u);
  return (ushort)(u >> 16);
}
__device__ __forceinline__ uint pack2bf(float a, float b) {
  return (uint)f2bf(a) | ((uint)f2bf(b) << 16);
}
// exp(s - 30) written identically in stats and attn kernels
__device__ __forceinline__ float pexp(float s) {
  return exp2f(fmaf(s, 1.4426950408889634f, -43.2808512266689f));
}

// ---------- ws layout (bytes) ----------
#define WS_XT    0UL
#define WS_D     16777216UL
#define WS_BT    33554432UL
#define WS_CT    35651584UL
#define WS_WCAT  37748736UL
#define WS_BCAT  38404096UL
#define WS_LINV  38406656UL

// ---------- kernel 1: pack weights to bf16 [640][512] + bias concat ----------
__global__ void k_prep_w(const float* __restrict__ Wb, const float* __restrict__ bb,
                         const float* __restrict__ Wc, const float* __restrict__ bc,
                         const float* __restrict__ Wd, const float* __restrict__ bd,
                         ushort* __restrict__ Wcat, float* __restrict__ bcat) {
  int idx = blockIdx.x * 256 + threadIdx.x;
  if (idx < 640 * 512) {
    int m = idx >> 9, k = idx & 511;
    float v = (m < 64) ? Wb[m * 512 + k] : (m < 128) ? Wc[(m - 64) * 512 + k] : Wd[(m - 128) * 512 + k];
    Wcat[idx] = f2bf(v);
  }
  if (idx < 640) {
    bcat[idx] = (idx < 64) ? bb[idx] : (idx < 128) ? bc[idx - 64] : bd[idx - 128];
  }
}

// ---------- kernel 2: transpose x [B][512][4096] f32 -> xT [B][4096][512] bf16 ----------
__global__ __launch_bounds__(256) void k_prep_xt(const float* __restrict__ x, ushort* __restrict__ xT) {
  __shared__ float tile[64][65];
  int bx = blockIdx.x;
  int b = bx >> 9;                  // 8*64 = 512 tiles per batch
  int c0 = ((bx >> 6) & 7) * 64;
  int n0 = (bx & 63) * 64;
  int t = threadIdx.x;
  const float* xb = x + (size_t)b * 512 * 4096;
#pragma unroll
  for (int p = 0; p < 4; ++p) {
    int cl = (t >> 4) + 16 * p;
    int nf = (t & 15) * 4;
    float4 v = *reinterpret_cast<const float4*>(xb + (size_t)(c0 + cl) * 4096 + n0 + nf);
    tile[cl][nf + 0] = v.x; tile[cl][nf + 1] = v.y; tile[cl][nf + 2] = v.z; tile[cl][nf + 3] = v.w;
  }
  __syncthreads();
  ushort* dst = xT + (size_t)b * 4096 * 512;
#pragma unroll
  for (int q = 0; q < 2; ++q) {
    int ch = t + 256 * q;
    int nl = ch >> 3;
    int cf = (ch & 7) * 8;
    uint4 o;
    o.x = pack2bf(tile[cf + 0][nl], tile[cf + 1][nl]);
    o.y = pack2bf(tile[cf + 2][nl], tile[cf + 3][nl]);
    o.z = pack2bf(tile[cf + 4][nl], tile[cf + 5][nl]);
    o.w = pack2bf(tile[cf + 6][nl], tile[cf + 7][nl]);
    *reinterpret_cast<uint4*>(dst + (size_t)(n0 + nl) * 512 + c0 + cf) = o;
  }
}

// ---------- kernel 3: projection GEMM [640 x 4096, K=512] per batch ----------
// rows 0-63 -> bT[n][k] (transposed), 64-127 -> cT[n][k], 128-639 -> d[c][n]
__global__ __launch_bounds__(256) void k_proj(const ushort* __restrict__ Wcat, const float* __restrict__ bcat,
                                              const ushort* __restrict__ xT, ushort* __restrict__ bT,
                                              ushort* __restrict__ cT, ushort* __restrict__ dmat) {
  int bx = blockIdx.x;
  int b = bx / 160;
  int r = bx % 160;
  int m0 = (r >> 5) * 128;    // 5 m-tiles
  int n0 = (r & 31) * 128;    // 32 n-tiles
  int t = threadIdx.x, l = t & 63, w = t >> 6;
  int wm = w >> 1, wn = w & 1, g = l >> 4, l15 = l & 15;
  const ushort* xb = xT + (size_t)b * 4096 * 512;
  f32x4 acc[4][4] = {};
  // prefetch first xT fragments (longer-latency stream)
  s16x8 bfn[4];
#pragma unroll
  for (int nt = 0; nt < 4; ++nt)
    bfn[nt] = *reinterpret_cast<const s16x8*>(xb + (size_t)(n0 + 64 * wn + 16 * nt + l15) * 512 + 8 * g);
  for (int k0 = 0; k0 < 512; k0 += 32) {
    s16x8 a[4], bf[4];
#pragma unroll
    for (int nt = 0; nt < 4; ++nt) bf[nt] = bfn[nt];
#pragma unroll
    for (int mt = 0; mt < 4; ++mt)
      a[mt] = *reinterpret_cast<const s16x8*>(Wcat + (size_t)(m0 + 64 * wm + 16 * mt + l15) * 512 + k0 + 8 * g);
    if (k0 + 32 < 512) {
#pragma unroll
      for (int nt = 0; nt < 4; ++nt)
        bfn[nt] = *reinterpret_cast<const s16x8*>(xb + (size_t)(n0 + 64 * wn + 16 * nt + l15) * 512 + k0 + 32 + 8 * g);
    }
#pragma unroll
    for (int mt = 0; mt < 4; ++mt)
#pragma unroll
      for (int nt = 0; nt < 4; ++nt)
        acc[mt][nt] = MFMA_BF16(a[mt], bf[nt], acc[mt][nt]);
  }
#pragma unroll
  for (int mt = 0; mt < 4; ++mt) {
    int mbase = m0 + 64 * wm + 16 * mt + 4 * g;
#pragma unroll
    for (int nt = 0; nt < 4; ++nt) {
      int n = n0 + 64 * wn + 16 * nt + l15;
      float v0 = acc[mt][nt][0] + bcat[mbase + 0];
      float v1 = acc[mt][nt][1] + bcat[mbase + 1];
      float v2 = acc[mt][nt][2] + bcat[mbase + 2];
      float v3 = acc[mt][nt][3] + bcat[mbase + 3];
      if (mbase < 64) {
        uint2 u; u.x = pack2bf(v0, v1); u.y = pack2bf(v2, v3);
        *reinterpret_cast<uint2*>(bT + ((size_t)b * 4096 + n) * 64 + mbase) = u;
      } else if (mbase < 128) {
        uint2 u; u.x = pack2bf(v0, v1); u.y = pack2bf(v2, v3);
        *reinterpret_cast<uint2*>(cT + ((size_t)b * 4096 + n) * 64 + (mbase - 64)) = u;
      } else {
        size_t base = ((size_t)b * 512 + (mbase - 128)) * 4096 + n;
        dmat[base + 0 * 4096] = f2bf(v0);
        dmat[base + 1 * 4096] = f2bf(v1);
        dmat[base + 2 * 4096] = f2bf(v2);
        dmat[base + 3 * 4096] = f2bf(v3);
      }
    }
  }
}

// ---------- kernel 4: row-sum stats  linv[b][i] = 1 / sum_j exp(s_ij - 30) ----------
__global__ __launch_bounds__(512) void k_stats(const ushort* __restrict__ bT, const ushort* __restrict__ cT,
                                               float* __restrict__ linv) {
  __shared__ float lsum[64];
  int bx = blockIdx.x;
  int b = bx >> 6;
  int i0 = (bx & 63) * 64;
  int t = threadIdx.x, l = t & 63, w = t >> 6;
  int wm = w >> 1, wn = w & 1, g = l >> 4, l15 = l & 15;
  if (t < 64) lsum[t] = 0.f;
  __syncthreads();
  const ushort* bTb = bT + (size_t)b * 4096 * 64;
  const ushort* cTb = cT + (size_t)b * 4096 * 64;
  const ushort* ar = bTb + (size_t)(i0 + 16 * wm + l15) * 64 + 8 * g;
  s16x8 a0 = *reinterpret_cast<const s16x8*>(ar);
  s16x8 a1 = *reinterpret_cast<const s16x8*>(ar + 32);
  float lacc[4] = {0.f, 0.f, 0.f, 0.f};
  // double-buffered cT fragment loads
  s16x8 b0n[4], b1n[4];
#pragma unroll
  for (int nt = 0; nt < 4; ++nt) {
    const ushort* cr = cTb + (size_t)(64 * wn + 16 * nt + l15) * 64 + 8 * g;
    b0n[nt] = *reinterpret_cast<const s16x8*>(cr);
    b1n[nt] = *reinterpret_cast<const s16x8*>(cr + 32);
  }
  for (int it = 0; it < 32; ++it) {
    s16x8 b0[4], b1[4];
#pragma unroll
    for (int nt = 0; nt < 4; ++nt) { b0[nt] = b0n[nt]; b1[nt] = b1n[nt]; }
    if (it + 1 < 32) {
      int jb = 64 * wn + 128 * (it + 1);
#pragma unroll
      for (int nt = 0; nt < 4; ++nt) {
        const ushort* cr = cTb + (size_t)(jb + 16 * nt + l15) * 64 + 8 * g;
        b0n[nt] = *reinterpret_cast<const s16x8*>(cr);
        b1n[nt] = *reinterpret_cast<const s16x8*>(cr + 32);
      }
    }
#pragma unroll
    for (int nt = 0; nt < 4; ++nt) {
      f32x4 s = {0.f, 0.f, 0.f, 0.f};
      s = MFMA_BF16(a0, b0[nt], s);
      s = MFMA_BF16(a1, b1[nt], s);
#pragma unroll
      for (int rr = 0; rr < 4; ++rr) lacc[rr] += pexp(s[rr]);
    }
  }
#pragma unroll
  for (int off = 1; off < 16; off <<= 1)
#pragma unroll
    for (int rr = 0; rr < 4; ++rr) lacc[rr] += __shfl_xor(lacc[rr], off);
  if (l15 == 0) {
#pragma unroll
    for (int rr = 0; rr < 4; ++rr) atomicAdd(&lsum[16 * wm + 4 * g + rr], lacc[rr]);
  }
  __syncthreads();
  if (t < 64) linv[(size_t)b * 4096 + i0 + t] = 1.0f / fmaxf(lsum[t], 1e-30f);
}

// ---------- kernel 5: fused  Y = d . softmaxP(bT,cT) ; out = x + Y ----------
// block tile: 128 c-rows x 128 j-cols, K-loop over i in steps of 64. 8 waves (4x2).
// Software-pipelined: next-iter bT/d/linv prefetched into regs; PT double-buffered
// in LDS -> ONE barrier per iteration.
__global__ __launch_bounds__(512) void k_attn(const ushort* __restrict__ bT, const ushort* __restrict__ cT,
                                              const ushort* __restrict__ dmat, const float* __restrict__ linv,
                                              const float* __restrict__ x, float* __restrict__ out) {
  // padded rows: 136 B stride (34 dwords)
  __shared__ char lds_raw[128 * 136 * 3];
  char* cT_lds = lds_raw;               // [128 j][64 k bf16], stride 136B
  char* PT0    = lds_raw + 128 * 136;   // [128 j][64 i bf16] double-buffered
  int bx = blockIdx.x;
  int b = bx >> 7;                      // 4*32 = 128 blocks per batch
  int m0 = ((bx >> 5) & 3) * 128;
  int n0 = (bx & 31) * 128;
  int t = threadIdx.x, l = t & 63, w = t >> 6;
  int wm = w >> 1, wn = w & 1, g = l >> 4, l15 = l & 15;
  const ushort* bTb = bT + (size_t)b * 4096 * 64;
  const ushort* cTb = cT + (size_t)b * 4096 * 64;
  const ushort* db  = dmat + (size_t)b * 512 * 4096;
  const float*  lvb = linv + (size_t)b * 4096;

  // stage cT block-tile [128][64] into padded LDS
#pragma unroll
  for (int q = 0; q < 2; ++q) {
    int id = t + 512 * q;
    int row = id >> 3, kc = id & 7;
    s16x8 v = *reinterpret_cast<const s16x8*>(cTb + (size_t)(n0 + row) * 64 + kc * 8);
    *reinterpret_cast<s16x8*>(cT_lds + row * 136 + kc * 16) = v;
  }

  // prefetch iteration 0 operands while cT staging completes
  const ushort* ar0 = bTb + (size_t)(16 * wm + l15) * 64 + 8 * g;
  const ushort* dr0 = db + (size_t)(m0 + 32 * wm + l15) * 4096 + 8 * g;
  const ushort* dr1 = db + (size_t)(m0 + 32 * wm + 16 + l15) * 4096 + 8 * g;
  s16x8 a0n = *reinterpret_cast<const s16x8*>(ar0);
  s16x8 a1n = *reinterpret_cast<const s16x8*>(ar0 + 32);
  float4 lvn = *reinterpret_cast<const float4*>(lvb + 16 * wm + 4 * g);
  s16x8 d00n = *reinterpret_cast<const s16x8*>(dr0);
  s16x8 d01n = *reinterpret_cast<const s16x8*>(dr0 + 32);
  s16x8 d10n = *reinterpret_cast<const s16x8*>(dr1);
  s16x8 d11n = *reinterpret_cast<const s16x8*>(dr1 + 32);
  __syncthreads();

  f32x4 yacc[2][4] = {};
  for (int i0 = 0; i0 < 4096; i0 += 64) {
    char* PTc = PT0 + ((i0 >> 6) & 1) * (128 * 136);
    // rotate pipeline registers
    s16x8 a0 = a0n, a1 = a1n;
    s16x8 d00 = d00n, d01 = d01n, d10 = d10n, d11 = d11n;
    float4 lv = lvn;
    // issue next iteration's global loads (hidden under scores+PV compute)
    if (i0 + 64 < 4096) {
      int i1 = i0 + 64;
      const ushort* ar = bTb + (size_t)(i1 + 16 * wm + l15) * 64 + 8 * g;
      a0n = *reinterpret_cast<const s16x8*>(ar);
      a1n = *reinterpret_cast<const s16x8*>(ar + 32);
      lvn = *reinterpret_cast<const float4*>(lvb + i1 + 16 * wm + 4 * g);
      const ushort* e0 = dr0 + i1;
      const ushort* e1 = dr1 + i1;
      d00n = *reinterpret_cast<const s16x8*>(e0);
      d01n = *reinterpret_cast<const s16x8*>(e0 + 32);
      d10n = *reinterpret_cast<const s16x8*>(e1);
      d11n = *reinterpret_cast<const s16x8*>(e1 + 32);
    }
    // ---- scores: S[64 i x 128 j]; wave (wm,wn) does i rows [16wm,+16), j cols [64wn,+64)
#pragma unroll
    for (int nt = 0; nt < 4; ++nt) {
      int jr = 64 * wn + 16 * nt + l15;
      s16x8 b0 = *reinterpret_cast<const s16x8*>(cT_lds + jr * 136 + 16 * g);
      s16x8 b1 = *reinterpret_cast<const s16x8*>(cT_lds + jr * 136 + 64 + 16 * g);
      f32x4 s = {0.f, 0.f, 0.f, 0.f};
      s = MFMA_BF16(a0, b0, s);
      s = MFMA_BF16(a1, b1, s);
      uint2 u;
      u.x = pack2bf(pexp(s[0]) * lv.x, pexp(s[1]) * lv.y);
      u.y = pack2bf(pexp(s[2]) * lv.z, pexp(s[3]) * lv.w);
      *reinterpret_cast<uint2*>(PTc + jr * 136 + (16 * wm + 4 * g) * 2) = u;
    }
    __syncthreads();
    // ---- PV: Y[128 c x 128 j] += d[:, i0..i0+64] * P ; wave does rows [32wm,+32), cols [64wn,+64)
#pragma unroll
    for (int ks = 0; ks < 2; ++ks) {
      s16x8 av0 = ks ? d01 : d00;
      s16x8 av1 = ks ? d11 : d10;
#pragma unroll
      for (int nt = 0; nt < 4; ++nt) {
        int jr = 64 * wn + 16 * nt + l15;
        s16x8 bv = *reinterpret_cast<const s16x8*>(PTc + jr * 136 + 64 * ks + 16 * g);
        yacc[0][nt] = MFMA_BF16(av0, bv, yacc[0][nt]);
        yacc[1][nt] = MFMA_BF16(av1, bv, yacc[1][nt]);
      }
    }
    // no second barrier: PT is double-buffered; next write targets the other
    // buffer, and the lgkmcnt(0) drain at the next barrier orders reads.
  }
  // ---- epilogue: out = x + Y
#pragma unroll
  for (int mt = 0; mt < 2; ++mt) {
    int cbase = m0 + 32 * wm + 16 * mt + 4 * g;
#pragma unroll
    for (int nt = 0; nt < 4; ++nt) {
      int n = n0 + 64 * wn + 16 * nt + l15;
#pragma unroll
      for (int rr = 0; rr < 4; ++rr) {
        size_t idx = ((size_t)b * 512 + cbase + rr) * 4096 + n;
        out[idx] = x[idx] + yacc[mt][nt][rr];
      }
    }
  }
}

extern "C" void kernel_launch(void* const* d_in, const int* in_sizes, int n_in,
                              void* d_out, int out_size, void* d_ws, size_t ws_size,
                              hipStream_t stream) {
  const float* x  = (const float*)d_in[0];
  const float* Wb = (const float*)d_in[1];
  const float* bb = (const float*)d_in[2];
  const float* Wc = (const float*)d_in[3];
  const float* bc = (const float*)d_in[4];
  const float* Wd = (const float*)d_in[5];
  const float* bd = (const float*)d_in[6];
  char* ws = (char*)d_ws;
  ushort* xT   = (ushort*)(ws + WS_XT);
  ushort* dmat = (ushort*)(ws + WS_D);
  ushort* bT   = (ushort*)(ws + WS_BT);
  ushort* cT   = (ushort*)(ws + WS_CT);
  ushort* Wcat = (ushort*)(ws + WS_WCAT);
  float*  bcat = (float*)(ws + WS_BCAT);
  float*  linv = (float*)(ws + WS_LINV);
  float*  out  = (float*)d_out;

  k_prep_w<<<1280, 256, 0, stream>>>(Wb, bb, Wc, bc, Wd, bd, Wcat, bcat);
  k_prep_xt<<<2048, 256, 0, stream>>>(x, xT);
  k_proj<<<640, 256, 0, stream>>>(Wcat, bcat, xT, bT, cT, dmat);
  k_stats<<<256, 512, 0, stream>>>(bT, cT, linv);
  k_attn<<<512, 512, 0, stream>>>(bT, cT, dmat, linv, x, out);
}

// Round 3
// 492.048 us; speedup vs baseline: 1.2303x; 1.1966x over previous
//
#include <hip/hip_runtime.h>
#include <hip/hip_bf16.h>

typedef float f32x4 __attribute__((ext_vector_type(4)));
typedef float f32x16 __attribute__((ext_vector_type(16)));
typedef short s16x8 __attribute__((ext_vector_type(8)));
typedef uint  u32x4 __attribute__((ext_vector_type(4)));

#define MFMA_BF16(a, b, c) __builtin_amdgcn_mfma_f32_16x16x32_bf16((a), (b), (c), 0, 0, 0)
#define MFMA32(a, b, c)    __builtin_amdgcn_mfma_f32_32x32x16_bf16((a), (b), (c), 0, 0, 0)

// ---------- helpers ----------
__device__ __forceinline__ ushort f2bf(float f) {
  uint u = __builtin_bit_cast(uint, f);
  u += 0x7FFFu + ((u >> 16) & 1u);
  return (ushort)(u >> 16);
}
__device__ __forceinline__ uint pack2bf(float a, float b) {
  return (uint)f2bf(a) | ((uint)f2bf(b) << 16);
}
// exp(s - 30) written identically in stats and attn kernels
__device__ __forceinline__ float pexp(float s) {
  return exp2f(fmaf(s, 1.4426950408889634f, -43.2808512266689f));
}
__device__ __forceinline__ uint cvtpk(float lo, float hi) {
  uint r;
  asm("v_cvt_pk_bf16_f32 %0, %1, %2" : "=v"(r) : "v"(lo), "v"(hi));
  return r;
}
__device__ __forceinline__ void plswap(uint& a, uint& b) {
  asm("v_permlane32_swap_b32 %0, %1" : "+v"(a), "+v"(b));
}

// ---------- ws layout (bytes) ----------
#define WS_XT    0UL
#define WS_D     16777216UL
#define WS_BT    33554432UL
#define WS_CT    35651584UL
#define WS_WCAT  37748736UL
#define WS_BCAT  38404096UL

// ---------- kernel 1: pack weights to bf16 [640][512] + bias concat ----------
__global__ void k_prep_w(const float* __restrict__ Wb, const float* __restrict__ bb,
                         const float* __restrict__ Wc, const float* __restrict__ bc,
                         const float* __restrict__ Wd, const float* __restrict__ bd,
                         ushort* __restrict__ Wcat, float* __restrict__ bcat) {
  int idx = blockIdx.x * 256 + threadIdx.x;
  if (idx < 640 * 512) {
    int m = idx >> 9, k = idx & 511;
    float v = (m < 64) ? Wb[m * 512 + k] : (m < 128) ? Wc[(m - 64) * 512 + k] : Wd[(m - 128) * 512 + k];
    Wcat[idx] = f2bf(v);
  }
  if (idx < 640) {
    bcat[idx] = (idx < 64) ? bb[idx] : (idx < 128) ? bc[idx - 64] : bd[idx - 128];
  }
}

// ---------- kernel 2: transpose x [B][512][4096] f32 -> xT [B][4096][512] bf16 ----------
__global__ __launch_bounds__(256) void k_prep_xt(const float* __restrict__ x, ushort* __restrict__ xT) {
  __shared__ float tile[64][65];
  int bx = blockIdx.x;
  int b = bx >> 9;                  // 8*64 = 512 tiles per batch
  int c0 = ((bx >> 6) & 7) * 64;
  int n0 = (bx & 63) * 64;
  int t = threadIdx.x;
  const float* xb = x + (size_t)b * 512 * 4096;
#pragma unroll
  for (int p = 0; p < 4; ++p) {
    int cl = (t >> 4) + 16 * p;
    int nf = (t & 15) * 4;
    float4 v = *reinterpret_cast<const float4*>(xb + (size_t)(c0 + cl) * 4096 + n0 + nf);
    tile[cl][nf + 0] = v.x; tile[cl][nf + 1] = v.y; tile[cl][nf + 2] = v.z; tile[cl][nf + 3] = v.w;
  }
  __syncthreads();
  ushort* dst = xT + (size_t)b * 4096 * 512;
#pragma unroll
  for (int q = 0; q < 2; ++q) {
    int ch = t + 256 * q;
    int nl = ch >> 3;
    int cf = (ch & 7) * 8;
    uint4 o;
    o.x = pack2bf(tile[cf + 0][nl], tile[cf + 1][nl]);
    o.y = pack2bf(tile[cf + 2][nl], tile[cf + 3][nl]);
    o.z = pack2bf(tile[cf + 4][nl], tile[cf + 5][nl]);
    o.w = pack2bf(tile[cf + 6][nl], tile[cf + 7][nl]);
    *reinterpret_cast<uint4*>(dst + (size_t)(n0 + nl) * 512 + c0 + cf) = o;
  }
}

// ---------- kernel 3: projection GEMM [640 x 4096, K=512] per batch ----------
__global__ __launch_bounds__(256) void k_proj(const ushort* __restrict__ Wcat, const float* __restrict__ bcat,
                                              const ushort* __restrict__ xT, ushort* __restrict__ bT,
                                              ushort* __restrict__ cT, ushort* __restrict__ dmat) {
  int bx = blockIdx.x;
  int b = bx / 160;
  int r = bx % 160;
  int m0 = (r >> 5) * 128;    // 5 m-tiles
  int n0 = (r & 31) * 128;    // 32 n-tiles
  int t = threadIdx.x, l = t & 63, w = t >> 6;
  int wm = w >> 1, wn = w & 1, g = l >> 4, l15 = l & 15;
  const ushort* xb = xT + (size_t)b * 4096 * 512;
  f32x4 acc[4][4] = {};
  s16x8 bfn[4];
#pragma unroll
  for (int nt = 0; nt < 4; ++nt)
    bfn[nt] = *reinterpret_cast<const s16x8*>(xb + (size_t)(n0 + 64 * wn + 16 * nt + l15) * 512 + 8 * g);
  for (int k0 = 0; k0 < 512; k0 += 32) {
    s16x8 a[4], bf[4];
#pragma unroll
    for (int nt = 0; nt < 4; ++nt) bf[nt] = bfn[nt];
#pragma unroll
    for (int mt = 0; mt < 4; ++mt)
      a[mt] = *reinterpret_cast<const s16x8*>(Wcat + (size_t)(m0 + 64 * wm + 16 * mt + l15) * 512 + k0 + 8 * g);
    if (k0 + 32 < 512) {
#pragma unroll
      for (int nt = 0; nt < 4; ++nt)
        bfn[nt] = *reinterpret_cast<const s16x8*>(xb + (size_t)(n0 + 64 * wn + 16 * nt + l15) * 512 + k0 + 32 + 8 * g);
    }
#pragma unroll
    for (int mt = 0; mt < 4; ++mt)
#pragma unroll
      for (int nt = 0; nt < 4; ++nt)
        acc[mt][nt] = MFMA_BF16(a[mt], bf[nt], acc[mt][nt]);
  }
#pragma unroll
  for (int mt = 0; mt < 4; ++mt) {
    int mbase = m0 + 64 * wm + 16 * mt + 4 * g;
#pragma unroll
    for (int nt = 0; nt < 4; ++nt) {
      int n = n0 + 64 * wn + 16 * nt + l15;
      float v0 = acc[mt][nt][0] + bcat[mbase + 0];
      float v1 = acc[mt][nt][1] + bcat[mbase + 1];
      float v2 = acc[mt][nt][2] + bcat[mbase + 2];
      float v3 = acc[mt][nt][3] + bcat[mbase + 3];
      if (mbase < 64) {
        uint2 u; u.x = pack2bf(v0, v1); u.y = pack2bf(v2, v3);
        *reinterpret_cast<uint2*>(bT + ((size_t)b * 4096 + n) * 64 + mbase) = u;
      } else if (mbase < 128) {
        uint2 u; u.x = pack2bf(v0, v1); u.y = pack2bf(v2, v3);
        *reinterpret_cast<uint2*>(cT + ((size_t)b * 4096 + n) * 64 + (mbase - 64)) = u;
      } else {
        size_t base = ((size_t)b * 512 + (mbase - 128)) * 4096 + n;
        dmat[base + 0 * 4096] = f2bf(v0);
        dmat[base + 1 * 4096] = f2bf(v1);
        dmat[base + 2 * 4096] = f2bf(v2);
        dmat[base + 3 * 4096] = f2bf(v3);
      }
    }
  }
}

// ---------- kernel 4: stats + fold  d[c,i] *= 1/sum_j exp(s_ij - 30) ----------
// Since Y[c,j] = sum_i d[c,i] * exp(s_ij-30) * linv[i], linv scales d's columns.
__global__ __launch_bounds__(512) void k_stats(const ushort* __restrict__ bT, const ushort* __restrict__ cT,
                                               ushort* __restrict__ dmat) {
  __shared__ float lsum[64];
  int bx = blockIdx.x;
  int b = bx >> 6;
  int i0 = (bx & 63) * 64;
  int t = threadIdx.x, l = t & 63, w = t >> 6;
  int wm = w >> 1, wn = w & 1, g = l >> 4, l15 = l & 15;
  if (t < 64) lsum[t] = 0.f;
  __syncthreads();
  const ushort* bTb = bT + (size_t)b * 4096 * 64;
  const ushort* cTb = cT + (size_t)b * 4096 * 64;
  const ushort* ar = bTb + (size_t)(i0 + 16 * wm + l15) * 64 + 8 * g;
  s16x8 a0 = *reinterpret_cast<const s16x8*>(ar);
  s16x8 a1 = *reinterpret_cast<const s16x8*>(ar + 32);
  float lacc[4] = {0.f, 0.f, 0.f, 0.f};
  s16x8 b0n[4], b1n[4];
#pragma unroll
  for (int nt = 0; nt < 4; ++nt) {
    const ushort* cr = cTb + (size_t)(64 * wn + 16 * nt + l15) * 64 + 8 * g;
    b0n[nt] = *reinterpret_cast<const s16x8*>(cr);
    b1n[nt] = *reinterpret_cast<const s16x8*>(cr + 32);
  }
  for (int it = 0; it < 32; ++it) {
    s16x8 b0[4], b1[4];
#pragma unroll
    for (int nt = 0; nt < 4; ++nt) { b0[nt] = b0n[nt]; b1[nt] = b1n[nt]; }
    if (it + 1 < 32) {
      int jb = 64 * wn + 128 * (it + 1);
#pragma unroll
      for (int nt = 0; nt < 4; ++nt) {
        const ushort* cr = cTb + (size_t)(jb + 16 * nt + l15) * 64 + 8 * g;
        b0n[nt] = *reinterpret_cast<const s16x8*>(cr);
        b1n[nt] = *reinterpret_cast<const s16x8*>(cr + 32);
      }
    }
#pragma unroll
    for (int nt = 0; nt < 4; ++nt) {
      f32x4 s = {0.f, 0.f, 0.f, 0.f};
      s = MFMA_BF16(a0, b0[nt], s);
      s = MFMA_BF16(a1, b1[nt], s);
#pragma unroll
      for (int rr = 0; rr < 4; ++rr) lacc[rr] += pexp(s[rr]);
    }
  }
#pragma unroll
  for (int off = 1; off < 16; off <<= 1)
#pragma unroll
    for (int rr = 0; rr < 4; ++rr) lacc[rr] += __shfl_xor(lacc[rr], off);
  if (l15 == 0) {
#pragma unroll
    for (int rr = 0; rr < 4; ++rr) atomicAdd(&lsum[16 * wm + 4 * g + rr], lacc[rr]);
  }
  __syncthreads();
  if (t < 64) lsum[t] = 1.0f / fmaxf(lsum[t], 1e-30f);
  __syncthreads();
  // scale dmat[b][t][i0..i0+64) in place (disjoint across blocks)
  ushort* drow = dmat + ((size_t)b * 512 + t) * 4096 + i0;
#pragma unroll
  for (int q = 0; q < 8; ++q) {
    s16x8 v = *reinterpret_cast<s16x8*>(drow + q * 8);
    s16x8 nv;
#pragma unroll
    for (int e = 0; e < 8; ++e) {
      float f = __builtin_bit_cast(float, ((uint)(ushort)v[e]) << 16) * lsum[q * 8 + e];
      nv[e] = (short)f2bf(f);
    }
    *reinterpret_cast<s16x8*>(drow + q * 8) = nv;
  }
}

// ---------- kernel 5: fused  Y = d' . exp(S-30) ; out = x + Y ----------
// Wave-independent, zero barriers, zero LDS. Each wave: (b, 128 c-rows, 32 j-cols),
// loops i in steps of 32. Scores via 32x32x16 MFMA; P stays in registers
// (cvt_pk + permlane32_swap converts scores-D layout to PV B-operand layout).
__global__ __launch_bounds__(256, 2) void k_attn(const ushort* __restrict__ bT, const ushort* __restrict__ cT,
                                                 const ushort* __restrict__ dmat,
                                                 const float* __restrict__ x, float* __restrict__ out) {
  int wid = blockIdx.x * 4 + (threadIdx.x >> 6);
  int l = threadIdx.x & 63;
  int l31 = l & 31, hi = l >> 5;
  int b  = wid >> 9;            // 512 wave-jobs per batch
  int cb = (wid >> 7) & 3;      // 4 c-blocks of 128
  int jb = wid & 127;           // 128 j-blocks of 32
  int c0 = cb * 128, j0 = jb * 32;
  const ushort* bTb = bT + (size_t)b * 4096 * 64;
  const ushort* cTb = cT + (size_t)b * 4096 * 64;
  const ushort* db  = dmat + (size_t)b * 512 * 4096;

  // cT fragments for this wave's 32 j's (fixed): lane n=j=l31, k = 16*kc + 8*hi + [0,8)
  s16x8 cf[4];
#pragma unroll
  for (int kc = 0; kc < 4; ++kc)
    cf[kc] = *reinterpret_cast<const s16x8*>(cTb + (size_t)(j0 + l31) * 64 + kc * 16 + hi * 8);

  const ushort* brow = bTb + (size_t)l31 * 64 + hi * 8;
  const ushort* drow = db + (size_t)(c0 + l31) * 4096 + hi * 8;

  // prefetch bT fragments for i0=0
  s16x8 bfn[4];
#pragma unroll
  for (int kc = 0; kc < 4; ++kc)
    bfn[kc] = *reinterpret_cast<const s16x8*>(brow + kc * 16);

  f32x16 zero16;
#pragma unroll
  for (int r = 0; r < 16; ++r) zero16[r] = 0.f;
  f32x16 yacc[4];
#pragma unroll
  for (int ct = 0; ct < 4; ++ct) yacc[ct] = zero16;

  for (int i0 = 0; i0 < 4096; i0 += 32) {
    s16x8 bf[4];
#pragma unroll
    for (int kc = 0; kc < 4; ++kc) bf[kc] = bfn[kc];
    // prefetch next i-step's bT (wraps harmlessly on last iter)
    int inext = (i0 + 32) & 4095;
#pragma unroll
    for (int kc = 0; kc < 4; ++kc)
      bfn[kc] = *reinterpret_cast<const s16x8*>(brow + (size_t)inext * 64 + kc * 16);
    // d fragments for this step: A lane m=c, k=i chunk ch: col = i0 + 16*ch + 8*hi
    s16x8 df[2][4];
#pragma unroll
    for (int ch = 0; ch < 2; ++ch)
#pragma unroll
      for (int ct = 0; ct < 4; ++ct)
        df[ch][ct] = *reinterpret_cast<const s16x8*>(drow + (size_t)ct * 32 * 4096 + i0 + ch * 16);
    // scores S[32 i][32 j], K=64: D col=j=l31, row=i=(r&3)+8*(r>>2)+4*hi
    f32x16 s = zero16;
#pragma unroll
    for (int kc = 0; kc < 4; ++kc) s = MFMA32(bf[kc], cf[kc], s);
    float p[16];
#pragma unroll
    for (int r = 0; r < 16; ++r) p[r] = pexp(s[r]);
    // pack to PV B-operand: lane (j=l31, hi) needs P[i0 + 16*ch + 8*hi + t][j], t=0..7
    uint x0 = cvtpk(p[0], p[1]),   y0 = cvtpk(p[4], p[5]);
    uint x1 = cvtpk(p[2], p[3]),   y1 = cvtpk(p[6], p[7]);
    uint x2 = cvtpk(p[8], p[9]),   y2 = cvtpk(p[12], p[13]);
    uint x3 = cvtpk(p[10], p[11]), y3 = cvtpk(p[14], p[15]);
    plswap(x0, y0); plswap(x1, y1); plswap(x2, y2); plswap(x3, y3);
    u32x4 pw0 = {x0, x1, y0, y1};   // chunk0 words 0..3
    u32x4 pw1 = {x2, x3, y2, y3};   // chunk1 words 0..3
    s16x8 pf0 = __builtin_bit_cast(s16x8, pw0);
    s16x8 pf1 = __builtin_bit_cast(s16x8, pw1);
    // PV: Y[c, j] += d'[c, i] * P[i, j]
#pragma unroll
    for (int ct = 0; ct < 4; ++ct) {
      yacc[ct] = MFMA32(df[0][ct], pf0, yacc[ct]);
      yacc[ct] = MFMA32(df[1][ct], pf1, yacc[ct]);
    }
  }
  // epilogue: out = x + Y
#pragma unroll
  for (int ct = 0; ct < 4; ++ct) {
#pragma unroll
    for (int r = 0; r < 16; ++r) {
      int row = c0 + 32 * ct + (r & 3) + 8 * (r >> 2) + 4 * hi;
      size_t idx = ((size_t)b * 512 + row) * 4096 + j0 + l31;
      out[idx] = x[idx] + yacc[ct][r];
    }
  }
}

extern "C" void kernel_launch(void* const* d_in, const int* in_sizes, int n_in,
                              void* d_out, int out_size, void* d_ws, size_t ws_size,
                              hipStream_t stream) {
  const float* x  = (const float*)d_in[0];
  const float* Wb = (const float*)d_in[1];
  const float* bb = (const float*)d_in[2];
  const float* Wc = (const float*)d_in[3];
  const float* bc = (const float*)d_in[4];
  const float* Wd = (const float*)d_in[5];
  const float* bd = (const float*)d_in[6];
  char* ws = (char*)d_ws;
  ushort* xT   = (ushort*)(ws + WS_XT);
  ushort* dmat = (ushort*)(ws + WS_D);
  ushort* bT   = (ushort*)(ws + WS_BT);
  ushort* cT   = (ushort*)(ws + WS_CT);
  ushort* Wcat = (ushort*)(ws + WS_WCAT);
  float*  bcat = (float*)(ws + WS_BCAT);
  float*  out  = (float*)d_out;

  k_prep_w<<<1280, 256, 0, stream>>>(Wb, bb, Wc, bc, Wd, bd, Wcat, bcat);
  k_prep_xt<<<2048, 256, 0, stream>>>(x, xT);
  k_proj<<<640, 256, 0, stream>>>(Wcat, bcat, xT, bT, cT, dmat);
  k_stats<<<256, 512, 0, stream>>>(bT, cT, dmat);
  k_attn<<<512, 256, 0, stream>>>(bT, cT, dmat, x, out);
}